// Round 13
// baseline (74.776 us; speedup 1.0000x reference)
//
#include <hip/hip_runtime.h>

#define B 16
#define N 1024
#define NF 128
#define NL 3
#define AH 64
#define HC 192   // NL*AH
#define FCH 128
#define NC 10
#define L2E 1.44269504088896f

typedef __attribute__((ext_vector_type(8))) short bf16x8;
typedef __attribute__((ext_vector_type(4))) float f32x4;
typedef __attribute__((ext_vector_type(4))) unsigned int u32x4;

static __device__ __forceinline__ unsigned short f2bf(float f) {
  unsigned int x = __builtin_bit_cast(unsigned int, f);
  return (unsigned short)((x + 0x7fffu + ((x >> 16) & 1u)) >> 16);   // RNE
}
static __device__ __forceinline__ float bf2f(unsigned short u) {
  unsigned int x = ((unsigned int)u) << 16;
  return __builtin_bit_cast(float, x);
}

// ---------------------------------------------------------------------------
// k_mask: adj -> fragment-order u16 bitmasks. Pure stream: each thread reads
// 4x16B contiguous (independent loads), packs u16, LDS transpose, coalesced
// store. mskf[(stripe*16+jt)*64+lane]: byte ks bits e = adj[stripe*16+(lane&15)]
// [jt*64+ks*32+(lane>>4)*8+e]. grid = B*64 = 1024 x 256.
// ---------------------------------------------------------------------------
__global__ __launch_bounds__(256) void k_mask(
    const float* __restrict__ adj, unsigned short* __restrict__ mskf)
{
  __shared__ unsigned short sm[16][66];
  const int t = threadIdx.x;
  const int stripe = blockIdx.x;                 // b*64 + iblk
  const float* ap = adj + (size_t)stripe * 16 * N;

  #pragma unroll
  for (int c = 0; c < 4; ++c) {
    const int row = c * 4 + (t >> 6);
    const int j0 = (t & 63) * 16;
    const float* p = ap + (size_t)row * N + j0;  // 64B contiguous per thread
    unsigned int bits = 0;
    #pragma unroll
    for (int q = 0; q < 4; ++q) {
      const uint4 u = *(const uint4*)(p + q * 4);
      bits |= (u.x ? 1u : 0u) << (q * 4 + 0);
      bits |= (u.y ? 1u : 0u) << (q * 4 + 1);
      bits |= (u.z ? 1u : 0u) << (q * 4 + 2);
      bits |= (u.w ? 1u : 0u) << (q * 4 + 3);
    }
    sm[row][t & 63] = (unsigned short)bits;      // bit e' = adj[row][(t&63)*16+e']
  }
  __syncthreads();

  #pragma unroll
  for (int cc = 0; cc < 4; ++cc) {
    const int o = cc * 256 + t;                  // 0..1023
    const int jt = o >> 6, lane_o = o & 63;
    const int lr = lane_o & 15, lg = lane_o >> 4;
    const int sh = (lg & 1) * 8;
    const unsigned int b0 = (sm[lr][jt * 4 + (lg >> 1)] >> sh) & 0xffu;
    const unsigned int b1 = (sm[lr][jt * 4 + 2 + (lg >> 1)] >> sh) & 0xffu;
    mskf[(size_t)stripe * 1024 + o] = (unsigned short)(b0 | (b1 << 8));
  }
}

// ---------------------------------------------------------------------------
// k_feat: 64 nodes/block; Ws staged per-layer into LDS with next-layer
// register prefetch; outputs h in FRAGMENT order h_f + f1/f2 f32 pre-scaled
// by log2e. grid = 256 x 256, 2 blocks/CU.
// ---------------------------------------------------------------------------
__global__ __launch_bounds__(256, 2) void k_feat(
    const float* __restrict__ x, const float* __restrict__ Ws,
    const float* __restrict__ a1, const float* __restrict__ a2,
    unsigned short* __restrict__ h_f, float* __restrict__ f1g,
    float* __restrict__ f2g)
{
  __shared__ float xs[64][132];                  // 33.8KB; hlds overlays later
  __shared__ unsigned short wl[2][64][136];      // 34.8KB hi/lo for one layer
  unsigned short (*hlds)[72] = (unsigned short(*)[72])&xs[0][0];  // 27.6KB
  const int t = threadIdx.x;
  const int n0g = blockIdx.x * 64;
  const int gb = n0g >> 10, nl0 = n0g & 1023;
  const int wv = t >> 6, lane = t & 63;
  const int lr = lane & 15, lg = lane >> 4;
  const int lrow = wv * 16 + lr;
  const int wcol = t & 63, woct = t >> 6;

#define LOADW(R, L) {                                                         \
    _Pragma("unroll")                                                         \
    for (int p = 0; p < 4; ++p) {                                             \
      const int oct = p * 4 + woct;                                           \
      _Pragma("unroll")                                                       \
      for (int i = 0; i < 8; ++i)                                             \
        R[p][i] = Ws[((size_t)(L) * NF + oct * 8 + i) * AH + wcol];           \
    } }
#define WRITEW(R) {                                                           \
    _Pragma("unroll")                                                         \
    for (int p = 0; p < 4; ++p) {                                             \
      const int oct = p * 4 + woct;                                           \
      bf16x8 hv, lv;                                                          \
      _Pragma("unroll")                                                       \
      for (int i = 0; i < 8; ++i) {                                           \
        const unsigned short hi = f2bf(R[p][i]);                              \
        hv[i] = (short)hi;                                                    \
        lv[i] = (short)f2bf(R[p][i] - bf2f(hi));                              \
      }                                                                       \
      *(bf16x8*)&wl[0][wcol][oct * 8] = hv;                                   \
      *(bf16x8*)&wl[1][wcol][oct * 8] = lv;                                   \
    } }
#define MFMAL(L) {                                                            \
    _Pragma("unroll")                                                         \
    for (int n2 = 0; n2 < 4; ++n2) {                                          \
      const int n = (L) * 4 + n2;                                             \
      _Pragma("unroll")                                                       \
      for (int kf = 0; kf < 4; ++kf) {                                        \
        const bf16x8 whi = *(const bf16x8*)&wl[0][n2 * 16 + lr][kf * 32 + lg * 8]; \
        const bf16x8 wlo = *(const bf16x8*)&wl[1][n2 * 16 + lr][kf * 32 + lg * 8]; \
        acc[n] = __builtin_amdgcn_mfma_f32_16x16x32_bf16(xhi[kf], whi, acc[n], 0, 0, 0); \
        acc[n] = __builtin_amdgcn_mfma_f32_16x16x32_bf16(xhi[kf], wlo, acc[n], 0, 0, 0); \
        acc[n] = __builtin_amdgcn_mfma_f32_16x16x32_bf16(xlo[kf], whi, acc[n], 0, 0, 0); \
      }                                                                       \
    } }

  float wrA[4][8], wrB[4][8];
  LOADW(wrA, 0);

  #pragma unroll
  for (int p = 0; p < 8; ++p) {
    const int q = p * 256 + t;
    const int row = q >> 5, c4 = (q & 31) * 4;
    *(float4*)&xs[row][c4] = *(const float4*)&x[(size_t)(n0g + row) * NF + c4];
  }
  __syncthreads();

  bf16x8 xhi[4], xlo[4];
  #pragma unroll
  for (int kf = 0; kf < 4; ++kf) {
    const float4 q0 = *(const float4*)&xs[lrow][kf * 32 + lg * 8];
    const float4 q1 = *(const float4*)&xs[lrow][kf * 32 + lg * 8 + 4];
    const float xv[8] = {q0.x, q0.y, q0.z, q0.w, q1.x, q1.y, q1.z, q1.w};
    #pragma unroll
    for (int e = 0; e < 8; ++e) {
      const unsigned short hi = f2bf(xv[e]);
      xhi[kf][e] = (short)hi;
      xlo[kf][e] = (short)f2bf(xv[e] - bf2f(hi));
    }
  }

  f32x4 acc[12];
  #pragma unroll
  for (int n = 0; n < 12; ++n) acc[n] = (f32x4){0.f, 0.f, 0.f, 0.f};

  WRITEW(wrA);
  LOADW(wrB, 1);
  __syncthreads();
  MFMAL(0);
  __syncthreads();
  WRITEW(wrB);
  LOADW(wrA, 2);
  __syncthreads();
  MFMAL(1);
  __syncthreads();
  WRITEW(wrA);
  __syncthreads();
  MFMAL(2);

#undef LOADW
#undef WRITEW
#undef MFMAL

  float s1[3][4], s2[3][4];
  #pragma unroll
  for (int l = 0; l < 3; ++l)
    #pragma unroll
    for (int r = 0; r < 4; ++r) { s1[l][r] = 0.f; s2[l][r] = 0.f; }
  #pragma unroll
  for (int n = 0; n < 12; ++n) {
    const int col = n * 16 + lr;
    const float a1v = a1[col] * L2E, a2v = a2[col] * L2E;
    const int l = n >> 2;
    #pragma unroll
    for (int r = 0; r < 4; ++r) {
      s1[l][r] += acc[n][r] * a1v;
      s2[l][r] += acc[n][r] * a2v;
    }
  }
  #pragma unroll
  for (int off = 1; off < 16; off <<= 1)
    #pragma unroll
    for (int l = 0; l < 3; ++l)
      #pragma unroll
      for (int r = 0; r < 4; ++r) {
        s1[l][r] += __shfl_xor(s1[l][r], off);
        s2[l][r] += __shfl_xor(s2[l][r], off);
      }
  if (lr == 0) {
    #pragma unroll
    for (int l = 0; l < 3; ++l)
      #pragma unroll
      for (int r = 0; r < 4; ++r) {
        const int rw = n0g + wv * 16 + lg * 4 + r;
        f1g[(size_t)l * (B * N) + rw] = s1[l][r];
        f2g[(size_t)l * (B * N) + rw] = s2[l][r];
      }
  }

  __syncthreads();                               // xs dead; hlds reuses it
  #pragma unroll
  for (int n = 0; n < 12; ++n) {
    const int col = n * 16 + lr;
    #pragma unroll
    for (int rp = 0; rp < 2; ++rp) {
      const unsigned int pr = (unsigned int)f2bf(acc[n][rp * 2]) |
                              ((unsigned int)f2bf(acc[n][rp * 2 + 1]) << 16);
      *(unsigned int*)&hlds[col][wv * 16 + lg * 4 + rp * 2] = pr;
    }
  }
  __syncthreads();
  #pragma unroll
  for (int p = 0; p < 6; ++p) {
    const int widx = p * 256 + t;
    const int lane_w = widx & 63;
    const int jb2 = (widx >> 6) & 1;
    const int n_w = (widx >> 7) & 3;
    const int l_w = widx >> 9;
    const int col = l_w * 64 + n_w * 16 + (lane_w & 15);
    const int jloc = jb2 * 32 + (lane_w >> 4) * 8;
    const size_t off =
        ((((size_t)(gb * 3 + l_w) * 4 + n_w) * 32 + (nl0 >> 5) + jb2) * 64 + lane_w) * 8;
    *(uint4*)&h_f[off] = *(const uint4*)&hlds[col][jloc];
  }
}

// ---------------------------------------------------------------------------
// k_att: fused 3-layer GAT attention + MFMA PV + ones-column denominator +
// relu + pool. ZERO barriers: fragment-order h_f + mskf from global (all
// coalesced, L2-resident), register double-buffer, phase-staggered circular
// j-loop, XCD-chunked swizzle. grid = 1024 x 192 (wave = layer, 16 rows).
// ---------------------------------------------------------------------------
__global__ __launch_bounds__(192, 3) void k_att(
    const unsigned short* __restrict__ mskf, const unsigned short* __restrict__ h_f,
    const float* __restrict__ f1, const float* __restrict__ f2,
    float* __restrict__ pooled)
{
  const int bid = blockIdx.x;
  const int blk = (bid & 7) * 128 + (bid >> 3);  // 8 XCDs x 128: 2 batches/XCD
  const int b = blk >> 6;
  const int i0 = (blk & 63) * 16;
  const int ph = ((bid * 5) & 7) * 128;          // per-block phase stagger
  const int t = threadIdx.x;
  const int l = t >> 6, lane = t & 63;
  const int lr = lane & 15, lg = lane >> 4;

  __shared__ float uvt[NL][2][N];                // 24 KB; wave-private slices

  // ---- prologue: u/v tables + full-N unmasked max (wave l = layer l) ----
  const float* f2p = f2 + (size_t)l * (B * N) + b * N;
  float mx = -1e30f;
  #pragma unroll
  for (int ch = 0; ch < 4; ++ch) {
    const int jb = ch * 256 + lane * 4;
    const float4 q = *(const float4*)&f2p[jb];
    mx = fmaxf(mx, fmaxf(fmaxf(q.x, q.y), fmaxf(q.z, q.w)));
    *(float4*)&uvt[l][0][jb] =
        (float4){exp2f(q.x), exp2f(q.y), exp2f(q.z), exp2f(q.w)};
    *(float4*)&uvt[l][1][jb] =
        (float4){exp2f(0.2f * q.x), exp2f(0.2f * q.y), exp2f(0.2f * q.z), exp2f(0.2f * q.w)};
  }
  #pragma unroll
  for (int off = 1; off < 64; off <<= 1) mx = fmaxf(mx, __shfl_xor(mx, off));
  // NOTE: no __syncthreads needed — uvt[l] is written and read only by wave l.

  const float f1r = f1[(size_t)l * (B * N) + b * N + i0 + lr];
  const float tts = f1r + mx;
  const float sr = fmaxf(tts, 0.f) + 0.2f * fminf(tts, 0.f);  // valid upper bound
  const float A = exp2f(f1r - sr);
  const float C = exp2f(0.2f * f1r - sr);

  const unsigned short* hfb = h_f + ((size_t)(b * 3 + l)) * 65536;
  const unsigned short* mrow = mskf + ((size_t)(b * 64 + (i0 >> 4))) * 1024;
  const float* ut = &uvt[l][0][0];
  const float* vt = &uvt[l][1][0];
  const bf16x8 ones = {(short)0x3F80, (short)0x3F80, (short)0x3F80, (short)0x3F80,
                       (short)0x3F80, (short)0x3F80, (short)0x3F80, (short)0x3F80};

  f32x4 acc[4];
  #pragma unroll
  for (int n = 0; n < 4; ++n) acc[n] = (f32x4){0.f, 0.f, 0.f, 0.f};
  f32x4 accd = (f32x4){0.f, 0.f, 0.f, 0.f};

#define LOADJ(BUF, MW, J) {                                                   \
    const int jj = (J) & (N - 1);                                             \
    MW = (unsigned int)mrow[(jj >> 6) * 64 + lane];                           \
    _Pragma("unroll")                                                         \
    for (int q = 0; q < 8; ++q) {                                             \
      const int ks = q >> 2, n = q & 3;                                       \
      BUF[q] = *(const bf16x8*)&hfb[(((size_t)n * 32 + (jj >> 5) + ks) * 64 + \
                                     lane) * 8];                              \
    } }

#define COMPJ(BUF, MW, J) {                                                   \
    _Pragma("unroll")                                                         \
    for (int ks = 0; ks < 2; ++ks) {                                          \
      const int kb = ((J) & (N - 1)) + ks * 32 + lg * 8;                      \
      const float4 u0 = *(const float4*)&ut[kb];                              \
      const float4 u1 = *(const float4*)&ut[kb + 4];                          \
      const float4 v0 = *(const float4*)&vt[kb];                              \
      const float4 v1 = *(const float4*)&vt[kb + 4];                          \
      const unsigned int mby = ((MW) >> (ks * 8)) & 0xffu;                    \
      const float uu[8] = {u0.x, u0.y, u0.z, u0.w, u1.x, u1.y, u1.z, u1.w};   \
      const float vv[8] = {v0.x, v0.y, v0.z, v0.w, v1.x, v1.y, v1.z, v1.w};   \
      unsigned int pk[4];                                                     \
      _Pragma("unroll")                                                       \
      for (int ep = 0; ep < 4; ++ep) {                                        \
        unsigned int pr[2];                                                   \
        _Pragma("unroll")                                                     \
        for (int h = 0; h < 2; ++h) {                                         \
          const int e = ep * 2 + h;                                           \
          /* leaky(t)=max(t,0.2t); exp2 monotone => P=max(A*u, C*v) */        \
          const float p = fmaxf(A * uu[e], C * vv[e]);                        \
          /* sign-extract bit e of mby -> all-ones/zero select mask */        \
          const unsigned int sel =                                            \
              (unsigned int)(((int)(mby << (31 - e))) >> 31);                 \
          pr[h] = (__builtin_bit_cast(unsigned int, p) + 0x8000u) & sel;      \
        }                                                                     \
        pk[ep] = __builtin_amdgcn_perm(pr[1], pr[0], 0x07060302u);            \
      }                                                                       \
      const u32x4 pkv = {pk[0], pk[1], pk[2], pk[3]};                         \
      const bf16x8 av = __builtin_bit_cast(bf16x8, pkv);                      \
      _Pragma("unroll")                                                       \
      for (int n = 0; n < 4; ++n)                                             \
        acc[n] = __builtin_amdgcn_mfma_f32_16x16x32_bf16(av, BUF[ks * 4 + n], \
                                                         acc[n], 0, 0, 0);    \
      accd = __builtin_amdgcn_mfma_f32_16x16x32_bf16(av, ones, accd, 0, 0, 0);\
    } }

#define SBAR __builtin_amdgcn_sched_barrier(0)

  bf16x8 bA[8], bB[8];
  unsigned int mwA, mwB;
  LOADJ(bA, mwA, ph);
  SBAR;
  for (int j0 = 0; j0 < N; j0 += 128) {
    LOADJ(bB, mwB, ph + j0 + 64);                // next tile in flight
    SBAR;
    COMPJ(bA, mwA, ph + j0);
    SBAR;
    LOADJ(bA, mwA, ph + j0 + 128);               // wraps harmlessly
    SBAR;
    COMPJ(bB, mwB, ph + j0 + 64);
    SBAR;
  }
#undef LOADJ
#undef COMPJ
#undef SBAR

  // epilogue: rows i0+lg*4+r owned by this lane's acc regs; denom from accd
  float dn[4];
  #pragma unroll
  for (int r = 0; r < 4; ++r) dn[r] = 1.f / fmaxf(accd[r], 1e-37f);

  #pragma unroll
  for (int n = 0; n < 4; ++n) {
    float csum = 0.f;
    #pragma unroll
    for (int r = 0; r < 4; ++r) csum += fmaxf(acc[n][r] * dn[r], 0.f);
    csum += __shfl_xor(csum, 16);
    csum += __shfl_xor(csum, 32);
    if (lg == 0) atomicAdd(&pooled[b * HC + l * 64 + n * 16 + lr], csum);
  }
}

// ---------------------------------------------------------------------------
// k_head: mean + FC1(relu) + FC2 + softmax.  grid = B.
// ---------------------------------------------------------------------------
__global__ __launch_bounds__(192) void k_head(
    const float* __restrict__ pooled_sums, const float* __restrict__ W1,
    const float* __restrict__ b1, const float* __restrict__ W2,
    const float* __restrict__ b2, float* __restrict__ out)
{
  const int b = blockIdx.x, t = threadIdx.x;
  __shared__ float pooled[HC];
  __shared__ float z[FCH];
  __shared__ float logits[NC];

  if (t < HC) pooled[t] = pooled_sums[b * HC + t] * (1.f / (float)N);
  __syncthreads();

  if (t < FCH) {
    float a = b1[t];
    #pragma unroll 4
    for (int f = 0; f < HC; ++f) a += pooled[f] * W1[(size_t)f * FCH + t];
    z[t] = a > 0.f ? a : 0.f;
  }
  __syncthreads();

  if (t < NC) {
    float a = b2[t];
    #pragma unroll 4
    for (int f = 0; f < FCH; ++f) a += z[f] * W2[(size_t)f * NC + t];
    logits[t] = a;
  }
  __syncthreads();

  if (t == 0) {
    float mxl = logits[0];
    for (int c = 1; c < NC; ++c) mxl = fmaxf(mxl, logits[c]);
    float e[NC], sum = 0.f;
    for (int c = 0; c < NC; ++c) { e[c] = __expf(logits[c] - mxl); sum += e[c]; }
    const float inv = 1.f / sum;
    for (int c = 0; c < NC; ++c) out[b * NC + c] = e[c] * inv;
  }
}

// ---------------------------------------------------------------------------
extern "C" void kernel_launch(void* const* d_in, const int* in_sizes, int n_in,
                              void* d_out, int out_size, void* d_ws, size_t ws_size,
                              hipStream_t stream)
{
  const float* x   = (const float*)d_in[0];
  const float* adj = (const float*)d_in[1];
  const float* Ws  = (const float*)d_in[2];
  const float* a1  = (const float*)d_in[3];
  const float* a2  = (const float*)d_in[4];
  const float* W1  = (const float*)d_in[5];
  const float* b1  = (const float*)d_in[6];
  const float* W2  = (const float*)d_in[7];
  const float* b2  = (const float*)d_in[8];
  float* out = (float*)d_out;

  // workspace layout (16B aligned chunks)
  unsigned short* h_f   = (unsigned short*)d_ws;                       // 6.29 MB
  float*          f1    = (float*)(h_f + (size_t)B * HC * N);          // 196 KB
  float*          f2    = f1 + (size_t)NL * B * N;                     // 196 KB
  float*          pooled= f2 + (size_t)NL * B * N;                     // 12 KB
  unsigned short* mskf  = (unsigned short*)(pooled + B * HC + 16);     // 2 MB

  hipMemsetAsync(pooled, 0, (size_t)B * HC * sizeof(float), stream);
  k_mask<<<B * 64, 256, 0, stream>>>(adj, mskf);
  k_feat<<<256, 256, 0, stream>>>(x, Ws, a1, a2, h_f, f1, f2);
  k_att <<<1024, 192, 0, stream>>>(mskf, h_f, f1, f2, pooled);
  k_head<<<B, 192, 0, stream>>>(pooled, W1, b1, W2, b2, out);
}

// Round 14
// 69.481 us; speedup vs baseline: 1.0762x; 1.0762x over previous
//
#include <hip/hip_runtime.h>

#define B 16
#define N 1024
#define NF 128
#define NL 3
#define AH 64
#define HC 192   // NL*AH
#define FCH 128
#define NC 10
#define L2E 1.44269504088896f

typedef __attribute__((ext_vector_type(8))) short bf16x8;
typedef __attribute__((ext_vector_type(4))) float f32x4;
typedef __attribute__((ext_vector_type(4))) unsigned int u32x4;

static __device__ __forceinline__ unsigned short f2bf(float f) {
  unsigned int x = __builtin_bit_cast(unsigned int, f);
  return (unsigned short)((x + 0x7fffu + ((x >> 16) & 1u)) >> 16);   // RNE
}
static __device__ __forceinline__ float bf2f(unsigned short u) {
  unsigned int x = ((unsigned int)u) << 16;
  return __builtin_bit_cast(float, x);
}

// ---------------------------------------------------------------------------
// k_mask: adj -> fragment-order u16 bitmasks. Pure stream. Block 0 also
// zeroes pooled (replaces the pathological 40us hipMemsetAsync fill).
// grid = B*64 = 1024 x 256.
// ---------------------------------------------------------------------------
__global__ __launch_bounds__(256) void k_mask(
    const float* __restrict__ adj, unsigned short* __restrict__ mskf,
    float* __restrict__ pooled)
{
  __shared__ unsigned short sm[16][66];
  const int t = threadIdx.x;
  const int stripe = blockIdx.x;                 // b*64 + iblk
  const float* ap = adj + (size_t)stripe * 16 * N;

  if (stripe == 0) {                             // zero pooled (12 KB)
    #pragma unroll
    for (int i = 0; i < 12; ++i) pooled[i * 256 + t] = 0.f;
  }

  #pragma unroll
  for (int c = 0; c < 4; ++c) {
    const int row = c * 4 + (t >> 6);
    const int j0 = (t & 63) * 16;
    const float* p = ap + (size_t)row * N + j0;  // 64B contiguous per thread
    unsigned int bits = 0;
    #pragma unroll
    for (int q = 0; q < 4; ++q) {
      const uint4 u = *(const uint4*)(p + q * 4);
      bits |= (u.x ? 1u : 0u) << (q * 4 + 0);
      bits |= (u.y ? 1u : 0u) << (q * 4 + 1);
      bits |= (u.z ? 1u : 0u) << (q * 4 + 2);
      bits |= (u.w ? 1u : 0u) << (q * 4 + 3);
    }
    sm[row][t & 63] = (unsigned short)bits;      // bit e' = adj[row][(t&63)*16+e']
  }
  __syncthreads();

  #pragma unroll
  for (int cc = 0; cc < 4; ++cc) {
    const int o = cc * 256 + t;                  // 0..1023
    const int jt = o >> 6, lane_o = o & 63;
    const int lr = lane_o & 15, lg = lane_o >> 4;
    const int sh = (lg & 1) * 8;
    const unsigned int b0 = (sm[lr][jt * 4 + (lg >> 1)] >> sh) & 0xffu;
    const unsigned int b1 = (sm[lr][jt * 4 + 2 + (lg >> 1)] >> sh) & 0xffu;
    mskf[(size_t)stripe * 1024 + o] = (unsigned short)(b0 | (b1 << 8));
  }
}

// ---------------------------------------------------------------------------
// k_feat: 64 nodes/block; Ws staged per-layer into LDS with next-layer
// register prefetch; outputs h in FRAGMENT order h_f + f1/f2 f32 pre-scaled
// by log2e. grid = 256 x 256, 2 blocks/CU.
// ---------------------------------------------------------------------------
__global__ __launch_bounds__(256, 2) void k_feat(
    const float* __restrict__ x, const float* __restrict__ Ws,
    const float* __restrict__ a1, const float* __restrict__ a2,
    unsigned short* __restrict__ h_f, float* __restrict__ f1g,
    float* __restrict__ f2g)
{
  __shared__ float xs[64][132];                  // 33.8KB; hlds overlays later
  __shared__ unsigned short wl[2][64][136];      // 34.8KB hi/lo for one layer
  unsigned short (*hlds)[72] = (unsigned short(*)[72])&xs[0][0];  // 27.6KB
  const int t = threadIdx.x;
  const int n0g = blockIdx.x * 64;
  const int gb = n0g >> 10, nl0 = n0g & 1023;
  const int wv = t >> 6, lane = t & 63;
  const int lr = lane & 15, lg = lane >> 4;
  const int lrow = wv * 16 + lr;
  const int wcol = t & 63, woct = t >> 6;

#define LOADW(R, L) {                                                         \
    _Pragma("unroll")                                                         \
    for (int p = 0; p < 4; ++p) {                                             \
      const int oct = p * 4 + woct;                                           \
      _Pragma("unroll")                                                       \
      for (int i = 0; i < 8; ++i)                                             \
        R[p][i] = Ws[((size_t)(L) * NF + oct * 8 + i) * AH + wcol];           \
    } }
#define WRITEW(R) {                                                           \
    _Pragma("unroll")                                                         \
    for (int p = 0; p < 4; ++p) {                                             \
      const int oct = p * 4 + woct;                                           \
      bf16x8 hv, lv;                                                          \
      _Pragma("unroll")                                                       \
      for (int i = 0; i < 8; ++i) {                                           \
        const unsigned short hi = f2bf(R[p][i]);                              \
        hv[i] = (short)hi;                                                    \
        lv[i] = (short)f2bf(R[p][i] - bf2f(hi));                              \
      }                                                                       \
      *(bf16x8*)&wl[0][wcol][oct * 8] = hv;                                   \
      *(bf16x8*)&wl[1][wcol][oct * 8] = lv;                                   \
    } }
#define MFMAL(L) {                                                            \
    _Pragma("unroll")                                                         \
    for (int n2 = 0; n2 < 4; ++n2) {                                          \
      const int n = (L) * 4 + n2;                                             \
      _Pragma("unroll")                                                       \
      for (int kf = 0; kf < 4; ++kf) {                                        \
        const bf16x8 whi = *(const bf16x8*)&wl[0][n2 * 16 + lr][kf * 32 + lg * 8]; \
        const bf16x8 wlo = *(const bf16x8*)&wl[1][n2 * 16 + lr][kf * 32 + lg * 8]; \
        acc[n] = __builtin_amdgcn_mfma_f32_16x16x32_bf16(xhi[kf], whi, acc[n], 0, 0, 0); \
        acc[n] = __builtin_amdgcn_mfma_f32_16x16x32_bf16(xhi[kf], wlo, acc[n], 0, 0, 0); \
        acc[n] = __builtin_amdgcn_mfma_f32_16x16x32_bf16(xlo[kf], whi, acc[n], 0, 0, 0); \
      }                                                                       \
    } }

  float wrA[4][8], wrB[4][8];
  LOADW(wrA, 0);

  #pragma unroll
  for (int p = 0; p < 8; ++p) {
    const int q = p * 256 + t;
    const int row = q >> 5, c4 = (q & 31) * 4;
    *(float4*)&xs[row][c4] = *(const float4*)&x[(size_t)(n0g + row) * NF + c4];
  }
  __syncthreads();

  bf16x8 xhi[4], xlo[4];
  #pragma unroll
  for (int kf = 0; kf < 4; ++kf) {
    const float4 q0 = *(const float4*)&xs[lrow][kf * 32 + lg * 8];
    const float4 q1 = *(const float4*)&xs[lrow][kf * 32 + lg * 8 + 4];
    const float xv[8] = {q0.x, q0.y, q0.z, q0.w, q1.x, q1.y, q1.z, q1.w};
    #pragma unroll
    for (int e = 0; e < 8; ++e) {
      const unsigned short hi = f2bf(xv[e]);
      xhi[kf][e] = (short)hi;
      xlo[kf][e] = (short)f2bf(xv[e] - bf2f(hi));
    }
  }

  f32x4 acc[12];
  #pragma unroll
  for (int n = 0; n < 12; ++n) acc[n] = (f32x4){0.f, 0.f, 0.f, 0.f};

  WRITEW(wrA);
  LOADW(wrB, 1);
  __syncthreads();
  MFMAL(0);
  __syncthreads();
  WRITEW(wrB);
  LOADW(wrA, 2);
  __syncthreads();
  MFMAL(1);
  __syncthreads();
  WRITEW(wrA);
  __syncthreads();
  MFMAL(2);

#undef LOADW
#undef WRITEW
#undef MFMAL

  float s1[3][4], s2[3][4];
  #pragma unroll
  for (int l = 0; l < 3; ++l)
    #pragma unroll
    for (int r = 0; r < 4; ++r) { s1[l][r] = 0.f; s2[l][r] = 0.f; }
  #pragma unroll
  for (int n = 0; n < 12; ++n) {
    const int col = n * 16 + lr;
    const float a1v = a1[col] * L2E, a2v = a2[col] * L2E;
    const int l = n >> 2;
    #pragma unroll
    for (int r = 0; r < 4; ++r) {
      s1[l][r] += acc[n][r] * a1v;
      s2[l][r] += acc[n][r] * a2v;
    }
  }
  #pragma unroll
  for (int off = 1; off < 16; off <<= 1)
    #pragma unroll
    for (int l = 0; l < 3; ++l)
      #pragma unroll
      for (int r = 0; r < 4; ++r) {
        s1[l][r] += __shfl_xor(s1[l][r], off);
        s2[l][r] += __shfl_xor(s2[l][r], off);
      }
  if (lr == 0) {
    #pragma unroll
    for (int l = 0; l < 3; ++l)
      #pragma unroll
      for (int r = 0; r < 4; ++r) {
        const int rw = n0g + wv * 16 + lg * 4 + r;
        f1g[(size_t)l * (B * N) + rw] = s1[l][r];
        f2g[(size_t)l * (B * N) + rw] = s2[l][r];
      }
  }

  __syncthreads();                               // xs dead; hlds reuses it
  #pragma unroll
  for (int n = 0; n < 12; ++n) {
    const int col = n * 16 + lr;
    #pragma unroll
    for (int rp = 0; rp < 2; ++rp) {
      const unsigned int pr = (unsigned int)f2bf(acc[n][rp * 2]) |
                              ((unsigned int)f2bf(acc[n][rp * 2 + 1]) << 16);
      *(unsigned int*)&hlds[col][wv * 16 + lg * 4 + rp * 2] = pr;
    }
  }
  __syncthreads();
  #pragma unroll
  for (int p = 0; p < 6; ++p) {
    const int widx = p * 256 + t;
    const int lane_w = widx & 63;
    const int jb2 = (widx >> 6) & 1;
    const int n_w = (widx >> 7) & 3;
    const int l_w = widx >> 9;
    const int col = l_w * 64 + n_w * 16 + (lane_w & 15);
    const int jloc = jb2 * 32 + (lane_w >> 4) * 8;
    const size_t off =
        ((((size_t)(gb * 3 + l_w) * 4 + n_w) * 32 + (nl0 >> 5) + jb2) * 64 + lane_w) * 8;
    *(uint4*)&h_f[off] = *(const uint4*)&hlds[col][jloc];
  }
}

// ---------------------------------------------------------------------------
// k_att: fused 3-layer GAT attention + MFMA PV + ones-column denominator +
// relu + pool. ZERO barriers: fragment-order h_f + mskf from global (all
// coalesced, L2-resident), register double-buffer, phase-staggered circular
// j-loop, XCD-chunked swizzle. grid = 1024 x 192 (wave = layer, 16 rows).
// ---------------------------------------------------------------------------
__global__ __launch_bounds__(192, 3) void k_att(
    const unsigned short* __restrict__ mskf, const unsigned short* __restrict__ h_f,
    const float* __restrict__ f1, const float* __restrict__ f2,
    float* __restrict__ pooled)
{
  const int bid = blockIdx.x;
  const int blk = (bid & 7) * 128 + (bid >> 3);  // 8 XCDs x 128: 2 batches/XCD
  const int b = blk >> 6;
  const int i0 = (blk & 63) * 16;
  const int ph = ((bid * 5) & 7) * 128;          // per-block phase stagger
  const int t = threadIdx.x;
  const int l = t >> 6, lane = t & 63;
  const int lr = lane & 15, lg = lane >> 4;

  __shared__ float uvt[NL][2][N];                // 24 KB; wave-private slices

  // ---- prologue: u/v tables + full-N unmasked max (wave l = layer l) ----
  const float* f2p = f2 + (size_t)l * (B * N) + b * N;
  float mx = -1e30f;
  #pragma unroll
  for (int ch = 0; ch < 4; ++ch) {
    const int jb = ch * 256 + lane * 4;
    const float4 q = *(const float4*)&f2p[jb];
    mx = fmaxf(mx, fmaxf(fmaxf(q.x, q.y), fmaxf(q.z, q.w)));
    *(float4*)&uvt[l][0][jb] =
        (float4){exp2f(q.x), exp2f(q.y), exp2f(q.z), exp2f(q.w)};
    *(float4*)&uvt[l][1][jb] =
        (float4){exp2f(0.2f * q.x), exp2f(0.2f * q.y), exp2f(0.2f * q.z), exp2f(0.2f * q.w)};
  }
  #pragma unroll
  for (int off = 1; off < 64; off <<= 1) mx = fmaxf(mx, __shfl_xor(mx, off));
  // NOTE: no __syncthreads needed — uvt[l] is written and read only by wave l.

  const float f1r = f1[(size_t)l * (B * N) + b * N + i0 + lr];
  const float tts = f1r + mx;
  const float sr = fmaxf(tts, 0.f) + 0.2f * fminf(tts, 0.f);  // valid upper bound
  const float A = exp2f(f1r - sr);
  const float C = exp2f(0.2f * f1r - sr);

  const unsigned short* hfb = h_f + ((size_t)(b * 3 + l)) * 65536;
  const unsigned short* mrow = mskf + ((size_t)(b * 64 + (i0 >> 4))) * 1024;
  const float* ut = &uvt[l][0][0];
  const float* vt = &uvt[l][1][0];
  const bf16x8 ones = {(short)0x3F80, (short)0x3F80, (short)0x3F80, (short)0x3F80,
                       (short)0x3F80, (short)0x3F80, (short)0x3F80, (short)0x3F80};

  f32x4 acc[4];
  #pragma unroll
  for (int n = 0; n < 4; ++n) acc[n] = (f32x4){0.f, 0.f, 0.f, 0.f};
  f32x4 accd = (f32x4){0.f, 0.f, 0.f, 0.f};

#define LOADJ(BUF, MW, J) {                                                   \
    const int jj = (J) & (N - 1);                                             \
    MW = (unsigned int)mrow[(jj >> 6) * 64 + lane];                           \
    _Pragma("unroll")                                                         \
    for (int q = 0; q < 8; ++q) {                                             \
      const int ks = q >> 2, n = q & 3;                                       \
      BUF[q] = *(const bf16x8*)&hfb[(((size_t)n * 32 + (jj >> 5) + ks) * 64 + \
                                     lane) * 8];                              \
    } }

#define COMPJ(BUF, MW, J) {                                                   \
    _Pragma("unroll")                                                         \
    for (int ks = 0; ks < 2; ++ks) {                                          \
      const int kb = ((J) & (N - 1)) + ks * 32 + lg * 8;                      \
      const float4 u0 = *(const float4*)&ut[kb];                              \
      const float4 u1 = *(const float4*)&ut[kb + 4];                          \
      const float4 v0 = *(const float4*)&vt[kb];                              \
      const float4 v1 = *(const float4*)&vt[kb + 4];                          \
      const unsigned int mby = ((MW) >> (ks * 8)) & 0xffu;                    \
      const float uu[8] = {u0.x, u0.y, u0.z, u0.w, u1.x, u1.y, u1.z, u1.w};   \
      const float vv[8] = {v0.x, v0.y, v0.z, v0.w, v1.x, v1.y, v1.z, v1.w};   \
      unsigned int pk[4];                                                     \
      _Pragma("unroll")                                                       \
      for (int ep = 0; ep < 4; ++ep) {                                        \
        unsigned int pr[2];                                                   \
        _Pragma("unroll")                                                     \
        for (int h = 0; h < 2; ++h) {                                         \
          const int e = ep * 2 + h;                                           \
          /* leaky(t)=max(t,0.2t); exp2 monotone => P=max(A*u, C*v) */        \
          const float p = fmaxf(A * uu[e], C * vv[e]);                        \
          /* sign-extract bit e of mby -> all-ones/zero select mask */        \
          const unsigned int sel =                                            \
              (unsigned int)(((int)(mby << (31 - e))) >> 31);                 \
          pr[h] = (__builtin_bit_cast(unsigned int, p) + 0x8000u) & sel;      \
        }                                                                     \
        pk[ep] = __builtin_amdgcn_perm(pr[1], pr[0], 0x07060302u);            \
      }                                                                       \
      const u32x4 pkv = {pk[0], pk[1], pk[2], pk[3]};                         \
      const bf16x8 av = __builtin_bit_cast(bf16x8, pkv);                      \
      _Pragma("unroll")                                                       \
      for (int n = 0; n < 4; ++n)                                             \
        acc[n] = __builtin_amdgcn_mfma_f32_16x16x32_bf16(av, BUF[ks * 4 + n], \
                                                         acc[n], 0, 0, 0);    \
      accd = __builtin_amdgcn_mfma_f32_16x16x32_bf16(av, ones, accd, 0, 0, 0);\
    } }

#define SBAR __builtin_amdgcn_sched_barrier(0)

  bf16x8 bA[8], bB[8];
  unsigned int mwA, mwB;
  LOADJ(bA, mwA, ph);
  SBAR;
  for (int j0 = 0; j0 < N; j0 += 128) {
    LOADJ(bB, mwB, ph + j0 + 64);                // next tile in flight
    SBAR;
    COMPJ(bA, mwA, ph + j0);
    SBAR;
    LOADJ(bA, mwA, ph + j0 + 128);               // wraps harmlessly
    SBAR;
    COMPJ(bB, mwB, ph + j0 + 64);
    SBAR;
  }
#undef LOADJ
#undef COMPJ
#undef SBAR

  // epilogue: rows i0+lg*4+r owned by this lane's acc regs; denom from accd
  float dn[4];
  #pragma unroll
  for (int r = 0; r < 4; ++r) dn[r] = 1.f / fmaxf(accd[r], 1e-37f);

  #pragma unroll
  for (int n = 0; n < 4; ++n) {
    float csum = 0.f;
    #pragma unroll
    for (int r = 0; r < 4; ++r) csum += fmaxf(acc[n][r] * dn[r], 0.f);
    csum += __shfl_xor(csum, 16);
    csum += __shfl_xor(csum, 32);
    if (lg == 0) atomicAdd(&pooled[b * HC + l * 64 + n * 16 + lr], csum);
  }
}

// ---------------------------------------------------------------------------
// k_head: mean + FC1(relu) + FC2 + softmax.  grid = B.
// ---------------------------------------------------------------------------
__global__ __launch_bounds__(192) void k_head(
    const float* __restrict__ pooled_sums, const float* __restrict__ W1,
    const float* __restrict__ b1, const float* __restrict__ W2,
    const float* __restrict__ b2, float* __restrict__ out)
{
  const int b = blockIdx.x, t = threadIdx.x;
  __shared__ float pooled[HC];
  __shared__ float z[FCH];
  __shared__ float logits[NC];

  if (t < HC) pooled[t] = pooled_sums[b * HC + t] * (1.f / (float)N);
  __syncthreads();

  if (t < FCH) {
    float a = b1[t];
    #pragma unroll 4
    for (int f = 0; f < HC; ++f) a += pooled[f] * W1[(size_t)f * FCH + t];
    z[t] = a > 0.f ? a : 0.f;
  }
  __syncthreads();

  if (t < NC) {
    float a = b2[t];
    #pragma unroll 4
    for (int f = 0; f < FCH; ++f) a += z[f] * W2[(size_t)f * NC + t];
    logits[t] = a;
  }
  __syncthreads();

  if (t == 0) {
    float mxl = logits[0];
    for (int c = 1; c < NC; ++c) mxl = fmaxf(mxl, logits[c]);
    float e[NC], sum = 0.f;
    for (int c = 0; c < NC; ++c) { e[c] = __expf(logits[c] - mxl); sum += e[c]; }
    const float inv = 1.f / sum;
    for (int c = 0; c < NC; ++c) out[b * NC + c] = e[c] * inv;
  }
}

// ---------------------------------------------------------------------------
extern "C" void kernel_launch(void* const* d_in, const int* in_sizes, int n_in,
                              void* d_out, int out_size, void* d_ws, size_t ws_size,
                              hipStream_t stream)
{
  const float* x   = (const float*)d_in[0];
  const float* adj = (const float*)d_in[1];
  const float* Ws  = (const float*)d_in[2];
  const float* a1  = (const float*)d_in[3];
  const float* a2  = (const float*)d_in[4];
  const float* W1  = (const float*)d_in[5];
  const float* b1  = (const float*)d_in[6];
  const float* W2  = (const float*)d_in[7];
  const float* b2  = (const float*)d_in[8];
  float* out = (float*)d_out;

  // workspace layout (16B aligned chunks)
  unsigned short* h_f   = (unsigned short*)d_ws;                       // 6.29 MB
  float*          f1    = (float*)(h_f + (size_t)B * HC * N);          // 196 KB
  float*          f2    = f1 + (size_t)NL * B * N;                     // 196 KB
  float*          pooled= f2 + (size_t)NL * B * N;                     // 12 KB
  unsigned short* mskf  = (unsigned short*)(pooled + B * HC + 16);     // 2 MB

  k_mask<<<B * 64, 256, 0, stream>>>(adj, mskf, pooled);
  k_feat<<<256, 256, 0, stream>>>(x, Ws, a1, a2, h_f, f1, f2);
  k_att <<<1024, 192, 0, stream>>>(mskf, h_f, f1, f2, pooled);
  k_head<<<B, 192, 0, stream>>>(pooled, W1, b1, W2, b2, out);
}

// Round 15
// 68.082 us; speedup vs baseline: 1.0983x; 1.0206x over previous
//
#include <hip/hip_runtime.h>

#define B 16
#define N 1024
#define NF 128
#define NL 3
#define AH 64
#define HC 192   // NL*AH
#define FCH 128
#define NC 10
#define L2E 1.44269504088896f

typedef __attribute__((ext_vector_type(8))) short bf16x8;
typedef __attribute__((ext_vector_type(4))) float f32x4;
typedef __attribute__((ext_vector_type(4))) unsigned int u32x4;

static __device__ __forceinline__ unsigned short f2bf(float f) {
  unsigned int x = __builtin_bit_cast(unsigned int, f);
  return (unsigned short)((x + 0x7fffu + ((x >> 16) & 1u)) >> 16);   // RNE
}
static __device__ __forceinline__ float bf2f(unsigned short u) {
  unsigned int x = ((unsigned int)u) << 16;
  return __builtin_bit_cast(float, x);
}

// ---------------------------------------------------------------------------
// k_mask: adj -> fragment-order u16 bitmasks. Pure stream. Block 0 also
// zeroes pooled. grid = B*64 = 1024 x 256.
// ---------------------------------------------------------------------------
__global__ __launch_bounds__(256) void k_mask(
    const float* __restrict__ adj, unsigned short* __restrict__ mskf,
    float* __restrict__ pooled)
{
  __shared__ unsigned short sm[16][66];
  const int t = threadIdx.x;
  const int stripe = blockIdx.x;                 // b*64 + iblk
  const float* ap = adj + (size_t)stripe * 16 * N;

  if (stripe == 0) {                             // zero pooled (12 KB)
    #pragma unroll
    for (int i = 0; i < 12; ++i) pooled[i * 256 + t] = 0.f;
  }

  #pragma unroll
  for (int c = 0; c < 4; ++c) {
    const int row = c * 4 + (t >> 6);
    const int j0 = (t & 63) * 16;
    const float* p = ap + (size_t)row * N + j0;  // 64B contiguous per thread
    unsigned int bits = 0;
    #pragma unroll
    for (int q = 0; q < 4; ++q) {
      const uint4 u = *(const uint4*)(p + q * 4);
      bits |= (u.x ? 1u : 0u) << (q * 4 + 0);
      bits |= (u.y ? 1u : 0u) << (q * 4 + 1);
      bits |= (u.z ? 1u : 0u) << (q * 4 + 2);
      bits |= (u.w ? 1u : 0u) << (q * 4 + 3);
    }
    sm[row][t & 63] = (unsigned short)bits;      // bit e' = adj[row][(t&63)*16+e']
  }
  __syncthreads();

  #pragma unroll
  for (int cc = 0; cc < 4; ++cc) {
    const int o = cc * 256 + t;                  // 0..1023
    const int jt = o >> 6, lane_o = o & 63;
    const int lr = lane_o & 15, lg = lane_o >> 4;
    const int sh = (lg & 1) * 8;
    const unsigned int b0 = (sm[lr][jt * 4 + (lg >> 1)] >> sh) & 0xffu;
    const unsigned int b1 = (sm[lr][jt * 4 + 2 + (lg >> 1)] >> sh) & 0xffu;
    mskf[(size_t)stripe * 1024 + o] = (unsigned short)(b0 | (b1 << 8));
  }
}

// ---------------------------------------------------------------------------
// k_feat: 64 nodes/block; Ws staged per-layer into LDS with next-layer
// register prefetch; outputs h in FRAGMENT order h_f + f1/f2 f32 pre-scaled
// by log2e. grid = 256 x 256, 2 blocks/CU.
// ---------------------------------------------------------------------------
__global__ __launch_bounds__(256, 2) void k_feat(
    const float* __restrict__ x, const float* __restrict__ Ws,
    const float* __restrict__ a1, const float* __restrict__ a2,
    unsigned short* __restrict__ h_f, float* __restrict__ f1g,
    float* __restrict__ f2g)
{
  __shared__ float xs[64][132];                  // 33.8KB; hlds overlays later
  __shared__ unsigned short wl[2][64][136];      // 34.8KB hi/lo for one layer
  unsigned short (*hlds)[72] = (unsigned short(*)[72])&xs[0][0];  // 27.6KB
  const int t = threadIdx.x;
  const int n0g = blockIdx.x * 64;
  const int gb = n0g >> 10, nl0 = n0g & 1023;
  const int wv = t >> 6, lane = t & 63;
  const int lr = lane & 15, lg = lane >> 4;
  const int lrow = wv * 16 + lr;
  const int wcol = t & 63, woct = t >> 6;

#define LOADW(R, L) {                                                         \
    _Pragma("unroll")                                                         \
    for (int p = 0; p < 4; ++p) {                                             \
      const int oct = p * 4 + woct;                                           \
      _Pragma("unroll")                                                       \
      for (int i = 0; i < 8; ++i)                                             \
        R[p][i] = Ws[((size_t)(L) * NF + oct * 8 + i) * AH + wcol];           \
    } }
#define WRITEW(R) {                                                           \
    _Pragma("unroll")                                                         \
    for (int p = 0; p < 4; ++p) {                                             \
      const int oct = p * 4 + woct;                                           \
      bf16x8 hv, lv;                                                          \
      _Pragma("unroll")                                                       \
      for (int i = 0; i < 8; ++i) {                                           \
        const unsigned short hi = f2bf(R[p][i]);                              \
        hv[i] = (short)hi;                                                    \
        lv[i] = (short)f2bf(R[p][i] - bf2f(hi));                              \
      }                                                                       \
      *(bf16x8*)&wl[0][wcol][oct * 8] = hv;                                   \
      *(bf16x8*)&wl[1][wcol][oct * 8] = lv;                                   \
    } }
#define MFMAL(L) {                                                            \
    _Pragma("unroll")                                                         \
    for (int n2 = 0; n2 < 4; ++n2) {                                          \
      const int n = (L) * 4 + n2;                                             \
      _Pragma("unroll")                                                       \
      for (int kf = 0; kf < 4; ++kf) {                                        \
        const bf16x8 whi = *(const bf16x8*)&wl[0][n2 * 16 + lr][kf * 32 + lg * 8]; \
        const bf16x8 wlo = *(const bf16x8*)&wl[1][n2 * 16 + lr][kf * 32 + lg * 8]; \
        acc[n] = __builtin_amdgcn_mfma_f32_16x16x32_bf16(xhi[kf], whi, acc[n], 0, 0, 0); \
        acc[n] = __builtin_amdgcn_mfma_f32_16x16x32_bf16(xhi[kf], wlo, acc[n], 0, 0, 0); \
        acc[n] = __builtin_amdgcn_mfma_f32_16x16x32_bf16(xlo[kf], whi, acc[n], 0, 0, 0); \
      }                                                                       \
    } }

  float wrA[4][8], wrB[4][8];
  LOADW(wrA, 0);

  #pragma unroll
  for (int p = 0; p < 8; ++p) {
    const int q = p * 256 + t;
    const int row = q >> 5, c4 = (q & 31) * 4;
    *(float4*)&xs[row][c4] = *(const float4*)&x[(size_t)(n0g + row) * NF + c4];
  }
  __syncthreads();

  bf16x8 xhi[4], xlo[4];
  #pragma unroll
  for (int kf = 0; kf < 4; ++kf) {
    const float4 q0 = *(const float4*)&xs[lrow][kf * 32 + lg * 8];
    const float4 q1 = *(const float4*)&xs[lrow][kf * 32 + lg * 8 + 4];
    const float xv[8] = {q0.x, q0.y, q0.z, q0.w, q1.x, q1.y, q1.z, q1.w};
    #pragma unroll
    for (int e = 0; e < 8; ++e) {
      const unsigned short hi = f2bf(xv[e]);
      xhi[kf][e] = (short)hi;
      xlo[kf][e] = (short)f2bf(xv[e] - bf2f(hi));
    }
  }

  f32x4 acc[12];
  #pragma unroll
  for (int n = 0; n < 12; ++n) acc[n] = (f32x4){0.f, 0.f, 0.f, 0.f};

  WRITEW(wrA);
  LOADW(wrB, 1);
  __syncthreads();
  MFMAL(0);
  __syncthreads();
  WRITEW(wrB);
  LOADW(wrA, 2);
  __syncthreads();
  MFMAL(1);
  __syncthreads();
  WRITEW(wrA);
  __syncthreads();
  MFMAL(2);

#undef LOADW
#undef WRITEW
#undef MFMAL

  float s1[3][4], s2[3][4];
  #pragma unroll
  for (int l = 0; l < 3; ++l)
    #pragma unroll
    for (int r = 0; r < 4; ++r) { s1[l][r] = 0.f; s2[l][r] = 0.f; }
  #pragma unroll
  for (int n = 0; n < 12; ++n) {
    const int col = n * 16 + lr;
    const float a1v = a1[col] * L2E, a2v = a2[col] * L2E;
    const int l = n >> 2;
    #pragma unroll
    for (int r = 0; r < 4; ++r) {
      s1[l][r] += acc[n][r] * a1v;
      s2[l][r] += acc[n][r] * a2v;
    }
  }
  #pragma unroll
  for (int off = 1; off < 16; off <<= 1)
    #pragma unroll
    for (int l = 0; l < 3; ++l)
      #pragma unroll
      for (int r = 0; r < 4; ++r) {
        s1[l][r] += __shfl_xor(s1[l][r], off);
        s2[l][r] += __shfl_xor(s2[l][r], off);
      }
  if (lr == 0) {
    #pragma unroll
    for (int l = 0; l < 3; ++l)
      #pragma unroll
      for (int r = 0; r < 4; ++r) {
        const int rw = n0g + wv * 16 + lg * 4 + r;
        f1g[(size_t)l * (B * N) + rw] = s1[l][r];
        f2g[(size_t)l * (B * N) + rw] = s2[l][r];
      }
  }

  __syncthreads();                               // xs dead; hlds reuses it
  #pragma unroll
  for (int n = 0; n < 12; ++n) {
    const int col = n * 16 + lr;
    #pragma unroll
    for (int rp = 0; rp < 2; ++rp) {
      const unsigned int pr = (unsigned int)f2bf(acc[n][rp * 2]) |
                              ((unsigned int)f2bf(acc[n][rp * 2 + 1]) << 16);
      *(unsigned int*)&hlds[col][wv * 16 + lg * 4 + rp * 2] = pr;
    }
  }
  __syncthreads();
  #pragma unroll
  for (int p = 0; p < 6; ++p) {
    const int widx = p * 256 + t;
    const int lane_w = widx & 63;
    const int jb2 = (widx >> 6) & 1;
    const int n_w = (widx >> 7) & 3;
    const int l_w = widx >> 9;
    const int col = l_w * 64 + n_w * 16 + (lane_w & 15);
    const int jloc = jb2 * 32 + (lane_w >> 4) * 8;
    const size_t off =
        ((((size_t)(gb * 3 + l_w) * 4 + n_w) * 32 + (nl0 >> 5) + jb2) * 64 + lane_w) * 8;
    *(uint4*)&h_f[off] = *(const uint4*)&hlds[col][jloc];
  }
}

// ---------------------------------------------------------------------------
// k_att: fused 3-layer GAT attention + MFMA PV + ones-column denominator +
// relu + pool. ONE WAVE PER BLOCK, 32 ROWS PER WAVE: B-fragments loaded once
// serve two row-sets (halves h_f L2 traffic 384->196 MB). Zero barriers,
// register double-buffer, phase-staggered circular j-loop, XCD chunking.
// grid = B*32*3 = 1536 x 64.
// ---------------------------------------------------------------------------
__global__ __launch_bounds__(64, 3) void k_att(
    const unsigned short* __restrict__ mskf, const unsigned short* __restrict__ h_f,
    const float* __restrict__ f1, const float* __restrict__ f2,
    float* __restrict__ pooled)
{
  const int bid = blockIdx.x;
  const int blk = (bid & 7) * 192 + (bid >> 3);  // 8 XCDs x 192: 2 batches/XCD
  const int b = blk / 96;
  const int rem = blk - b * 96;
  const int l = rem >> 5;                        // layer
  const int i0 = (rem & 31) * 32;                // 32-row stripe
  const int ph = ((bid * 5) & 7) * 128;          // per-block phase stagger
  const int lane = threadIdx.x;
  const int lr = lane & 15, lg = lane >> 4;

  __shared__ float uvt[2][N];                    // 8 KB wave-private tables

  // ---- prologue: u/v tables + full-N unmasked max ----
  const float* f2p = f2 + (size_t)l * (B * N) + b * N;
  float mx = -1e30f;
  #pragma unroll
  for (int ch = 0; ch < 4; ++ch) {
    const int jb = ch * 256 + lane * 4;
    const float4 q = *(const float4*)&f2p[jb];
    mx = fmaxf(mx, fmaxf(fmaxf(q.x, q.y), fmaxf(q.z, q.w)));
    *(float4*)&uvt[0][jb] =
        (float4){exp2f(q.x), exp2f(q.y), exp2f(q.z), exp2f(q.w)};
    *(float4*)&uvt[1][jb] =
        (float4){exp2f(0.2f * q.x), exp2f(0.2f * q.y), exp2f(0.2f * q.z), exp2f(0.2f * q.w)};
  }
  #pragma unroll
  for (int off = 1; off < 64; off <<= 1) mx = fmaxf(mx, __shfl_xor(mx, off));

  // two row-sets: rows i0+lr (set 0) and i0+16+lr (set 1)
  const float f1r0 = f1[(size_t)l * (B * N) + b * N + i0 + lr];
  const float f1r1 = f1[(size_t)l * (B * N) + b * N + i0 + 16 + lr];
  const float tt0 = f1r0 + mx, tt1 = f1r1 + mx;
  const float sr0 = fmaxf(tt0, 0.f) + 0.2f * fminf(tt0, 0.f);
  const float sr1 = fmaxf(tt1, 0.f) + 0.2f * fminf(tt1, 0.f);
  const float A0 = exp2f(f1r0 - sr0), C0 = exp2f(0.2f * f1r0 - sr0);
  const float A1 = exp2f(f1r1 - sr1), C1 = exp2f(0.2f * f1r1 - sr1);

  const unsigned short* hfb = h_f + ((size_t)(b * 3 + l)) * 65536;
  const unsigned short* mrow = mskf + ((size_t)(b * 64 + (i0 >> 4))) * 1024;
  const float* ut = &uvt[0][0];
  const float* vt = &uvt[1][0];
  const bf16x8 ones = {(short)0x3F80, (short)0x3F80, (short)0x3F80, (short)0x3F80,
                       (short)0x3F80, (short)0x3F80, (short)0x3F80, (short)0x3F80};

  f32x4 acc0[4], acc1[4];
  #pragma unroll
  for (int n = 0; n < 4; ++n) {
    acc0[n] = (f32x4){0.f, 0.f, 0.f, 0.f};
    acc1[n] = (f32x4){0.f, 0.f, 0.f, 0.f};
  }
  f32x4 accd0 = (f32x4){0.f, 0.f, 0.f, 0.f};
  f32x4 accd1 = (f32x4){0.f, 0.f, 0.f, 0.f};

#define LOADJ(BUF, MW0, MW1, J) {                                             \
    const int jj = (J) & (N - 1);                                             \
    MW0 = (unsigned int)mrow[(jj >> 6) * 64 + lane];                          \
    MW1 = (unsigned int)mrow[1024 + (jj >> 6) * 64 + lane];                   \
    _Pragma("unroll")                                                         \
    for (int q = 0; q < 8; ++q) {                                             \
      const int ks = q >> 2, n = q & 3;                                       \
      BUF[q] = *(const bf16x8*)&hfb[(((size_t)n * 32 + (jj >> 5) + ks) * 64 + \
                                     lane) * 8];                              \
    } }

#define PGEN(AV, Aw, Cw, MB) {                                                \
    unsigned int pk[4];                                                       \
    _Pragma("unroll")                                                         \
    for (int ep = 0; ep < 4; ++ep) {                                          \
      unsigned int pr[2];                                                     \
      _Pragma("unroll")                                                       \
      for (int h = 0; h < 2; ++h) {                                           \
        const int e = ep * 2 + h;                                             \
        const float p = fmaxf((Aw) * uu[e], (Cw) * vv[e]);                    \
        const unsigned int sel =                                              \
            (unsigned int)(((int)((MB) << (31 - e))) >> 31);                  \
        pr[h] = (__builtin_bit_cast(unsigned int, p) + 0x8000u) & sel;        \
      }                                                                       \
      pk[ep] = __builtin_amdgcn_perm(pr[1], pr[0], 0x07060302u);              \
    }                                                                         \
    const u32x4 pkv = {pk[0], pk[1], pk[2], pk[3]};                           \
    AV = __builtin_bit_cast(bf16x8, pkv);                                     \
  }

#define COMPJ(BUF, MW0, MW1, J) {                                             \
    _Pragma("unroll")                                                         \
    for (int ks = 0; ks < 2; ++ks) {                                          \
      const int kb = ((J) & (N - 1)) + ks * 32 + lg * 8;                      \
      const float4 u0 = *(const float4*)&ut[kb];                              \
      const float4 u1 = *(const float4*)&ut[kb + 4];                          \
      const float4 v0 = *(const float4*)&vt[kb];                              \
      const float4 v1 = *(const float4*)&vt[kb + 4];                          \
      const unsigned int mb0 = ((MW0) >> (ks * 8)) & 0xffu;                   \
      const unsigned int mb1 = ((MW1) >> (ks * 8)) & 0xffu;                   \
      const float uu[8] = {u0.x, u0.y, u0.z, u0.w, u1.x, u1.y, u1.z, u1.w};   \
      const float vv[8] = {v0.x, v0.y, v0.z, v0.w, v1.x, v1.y, v1.z, v1.w};   \
      bf16x8 av0, av1;                                                        \
      PGEN(av0, A0, C0, mb0);                                                 \
      PGEN(av1, A1, C1, mb1);                                                 \
      _Pragma("unroll")                                                       \
      for (int n = 0; n < 4; ++n) {                                           \
        acc0[n] = __builtin_amdgcn_mfma_f32_16x16x32_bf16(av0, BUF[ks * 4 + n],\
                                                          acc0[n], 0, 0, 0);  \
        acc1[n] = __builtin_amdgcn_mfma_f32_16x16x32_bf16(av1, BUF[ks * 4 + n],\
                                                          acc1[n], 0, 0, 0);  \
      }                                                                       \
      accd0 = __builtin_amdgcn_mfma_f32_16x16x32_bf16(av0, ones, accd0, 0, 0, 0);\
      accd1 = __builtin_amdgcn_mfma_f32_16x16x32_bf16(av1, ones, accd1, 0, 0, 0);\
    } }

#define SBAR __builtin_amdgcn_sched_barrier(0)

  bf16x8 bA[8], bB[8];
  unsigned int mwA0, mwA1, mwB0, mwB1;
  LOADJ(bA, mwA0, mwA1, ph);
  SBAR;
  for (int j0 = 0; j0 < N; j0 += 128) {
    LOADJ(bB, mwB0, mwB1, ph + j0 + 64);         // next tile in flight
    SBAR;
    COMPJ(bA, mwA0, mwA1, ph + j0);
    SBAR;
    LOADJ(bA, mwA0, mwA1, ph + j0 + 128);        // wraps harmlessly
    SBAR;
    COMPJ(bB, mwB0, mwB1, ph + j0 + 64);
    SBAR;
  }
#undef LOADJ
#undef PGEN
#undef COMPJ
#undef SBAR

  // epilogue: set0 rows i0+lg*4+r, set1 rows i0+16+lg*4+r; cols n*16+lr
  float dn0[4], dn1[4];
  #pragma unroll
  for (int r = 0; r < 4; ++r) {
    dn0[r] = 1.f / fmaxf(accd0[r], 1e-37f);
    dn1[r] = 1.f / fmaxf(accd1[r], 1e-37f);
  }

  #pragma unroll
  for (int n = 0; n < 4; ++n) {
    float csum = 0.f;
    #pragma unroll
    for (int r = 0; r < 4; ++r) {
      csum += fmaxf(acc0[n][r] * dn0[r], 0.f);
      csum += fmaxf(acc1[n][r] * dn1[r], 0.f);
    }
    csum += __shfl_xor(csum, 16);
    csum += __shfl_xor(csum, 32);
    if (lg == 0) atomicAdd(&pooled[b * HC + l * 64 + n * 16 + lr], csum);
  }
}

// ---------------------------------------------------------------------------
// k_head: mean + FC1(relu) + FC2 + softmax.  grid = B.
// ---------------------------------------------------------------------------
__global__ __launch_bounds__(192) void k_head(
    const float* __restrict__ pooled_sums, const float* __restrict__ W1,
    const float* __restrict__ b1, const float* __restrict__ W2,
    const float* __restrict__ b2, float* __restrict__ out)
{
  const int b = blockIdx.x, t = threadIdx.x;
  __shared__ float pooled[HC];
  __shared__ float z[FCH];
  __shared__ float logits[NC];

  if (t < HC) pooled[t] = pooled_sums[b * HC + t] * (1.f / (float)N);
  __syncthreads();

  if (t < FCH) {
    float a = b1[t];
    #pragma unroll 4
    for (int f = 0; f < HC; ++f) a += pooled[f] * W1[(size_t)f * FCH + t];
    z[t] = a > 0.f ? a : 0.f;
  }
  __syncthreads();

  if (t < NC) {
    float a = b2[t];
    #pragma unroll 4
    for (int f = 0; f < FCH; ++f) a += z[f] * W2[(size_t)f * NC + t];
    logits[t] = a;
  }
  __syncthreads();

  if (t == 0) {
    float mxl = logits[0];
    for (int c = 1; c < NC; ++c) mxl = fmaxf(mxl, logits[c]);
    float e[NC], sum = 0.f;
    for (int c = 0; c < NC; ++c) { e[c] = __expf(logits[c] - mxl); sum += e[c]; }
    const float inv = 1.f / sum;
    for (int c = 0; c < NC; ++c) out[b * NC + c] = e[c] * inv;
  }
}

// ---------------------------------------------------------------------------
extern "C" void kernel_launch(void* const* d_in, const int* in_sizes, int n_in,
                              void* d_out, int out_size, void* d_ws, size_t ws_size,
                              hipStream_t stream)
{
  const float* x   = (const float*)d_in[0];
  const float* adj = (const float*)d_in[1];
  const float* Ws  = (const float*)d_in[2];
  const float* a1  = (const float*)d_in[3];
  const float* a2  = (const float*)d_in[4];
  const float* W1  = (const float*)d_in[5];
  const float* b1  = (const float*)d_in[6];
  const float* W2  = (const float*)d_in[7];
  const float* b2  = (const float*)d_in[8];
  float* out = (float*)d_out;

  // workspace layout (16B aligned chunks)
  unsigned short* h_f   = (unsigned short*)d_ws;                       // 6.29 MB
  float*          f1    = (float*)(h_f + (size_t)B * HC * N);          // 196 KB
  float*          f2    = f1 + (size_t)NL * B * N;                     // 196 KB
  float*          pooled= f2 + (size_t)NL * B * N;                     // 12 KB
  unsigned short* mskf  = (unsigned short*)(pooled + B * HC + 16);     // 2 MB

  k_mask<<<B * 64, 256, 0, stream>>>(adj, mskf, pooled);
  k_feat<<<256, 256, 0, stream>>>(x, Ws, a1, a2, h_f, f1, f2);
  k_att <<<B * 32 * 3, 64, 0, stream>>>(mskf, h_f, f1, f2, pooled);
  k_head<<<B, 192, 0, stream>>>(pooled, W1, b1, W2, b2, out);
}